// Round 1
// baseline (2050.914 us; speedup 1.0000x reference)
//
#include <hip/hip_runtime.h>
#include <hip/hip_bf16.h>
#include <math.h>

#define LOWEST_FREQ (30.0f / 11025.0f)

__device__ __forceinline__ float fast_sin_rev(float rev) {
#if __has_builtin(__builtin_amdgcn_sinf)
    return __builtin_amdgcn_sinf(rev);   // v_sin_f32: sin(2*pi*rev)
#else
    return __sinf(rev * 6.28318530717958647692f);
#endif
}
__device__ __forceinline__ float fast_cos_rev(float rev) {
#if __has_builtin(__builtin_amdgcn_cosf)
    return __builtin_amdgcn_cosf(rev);
#else
    return __cosf(rev * 6.28318530717958647692f);
#endif
}
__device__ __forceinline__ float lrelu(float x) { return x >= 0.f ? x : 0.2f * x; }

// ---------------- conv_in: 1ch -> 112ch 3x3 + concat pos (16ch) ----------------
__global__ __launch_bounds__(256) void conv_in_kernel(
    const float* __restrict__ x, const float* __restrict__ wi,
    const float* __restrict__ bi, const float* __restrict__ pos,
    float* __restrict__ out, int total)
{
    int idx = blockIdx.x * 256 + threadIdx.x;
    if (idx >= total) return;
    int pix = idx & 16383;
    int c   = (idx >> 14) & 127;
    int b   = idx >> 21;
    int y = pix >> 7, xx = pix & 127;
    float v;
    if (c < 112) {
        float acc = bi[c];
        const float* xb = x + (size_t)b * 16384;
        const float* wc = wi + c * 9;
        #pragma unroll
        for (int ky = 0; ky < 3; ++ky) {
            int gy = y + ky - 1;
            if ((unsigned)gy < 128u) {
                #pragma unroll
                for (int kx = 0; kx < 3; ++kx) {
                    int gx = xx + kx - 1;
                    if ((unsigned)gx < 128u)
                        acc = fmaf(wc[ky * 3 + kx], xb[gy * 128 + gx], acc);
                }
            }
        }
        v = acc;
    } else {
        v = pos[(c - 112) * 16384 + pix];
    }
    out[idx] = v;
}

// ---------------- generic 3x3 conv, 128->128 channels ----------------
// block = 256 threads = 16x16 output pixels; OCT out-channels per block.
template<int STRIDE, int ICCH, int OCT, bool RELU>
__global__ __launch_bounds__(256) void conv3x3_k(
    const float* __restrict__ in, const float* __restrict__ w,
    const float* __restrict__ bias, float* __restrict__ out,
    int Hin, int Win)
{
    constexpr int TW = (STRIDE == 1) ? 18 : 33;
    const int Hout = Hin / STRIDE;
    const int Wout = Win / STRIDE;
    __shared__ float sIn[ICCH][TW][TW];
    const int tid = threadIdx.x;
    const int tx = tid & 15, ty = tid >> 4;
    const int b   = blockIdx.z / (128 / OCT);
    const int ocb = (blockIdx.z % (128 / OCT)) * OCT;
    const int iy0 = blockIdx.y * 16 * STRIDE - 1;
    const int ix0 = blockIdx.x * 16 * STRIDE - 1;
    const size_t HW = (size_t)Hin * Win;

    float acc[OCT];
    #pragma unroll
    for (int i = 0; i < OCT; ++i) acc[i] = 0.f;

    for (int ic0 = 0; ic0 < 128; ic0 += ICCH) {
        const float* inb = in + ((size_t)b * 128 + ic0) * HW;
        constexpr int TOT = ICCH * TW * TW;
        for (int s = tid; s < TOT; s += 256) {
            int icl = s / (TW * TW);
            int rem = s - icl * (TW * TW);
            int r = rem / TW;
            int c = rem - r * TW;
            int gy = iy0 + r, gx = ix0 + c;
            float v = 0.f;
            if ((unsigned)gy < (unsigned)Hin && (unsigned)gx < (unsigned)Win)
                v = inb[icl * HW + (size_t)gy * Win + gx];
            sIn[icl][r][c] = v;
        }
        __syncthreads();
        #pragma unroll
        for (int icl = 0; icl < ICCH; ++icl) {
            const int ry = ty * STRIDE, rx = tx * STRIDE;
            float v00 = sIn[icl][ry + 0][rx + 0];
            float v01 = sIn[icl][ry + 0][rx + 1];
            float v02 = sIn[icl][ry + 0][rx + 2];
            float v10 = sIn[icl][ry + 1][rx + 0];
            float v11 = sIn[icl][ry + 1][rx + 1];
            float v12 = sIn[icl][ry + 1][rx + 2];
            float v20 = sIn[icl][ry + 2][rx + 0];
            float v21 = sIn[icl][ry + 2][rx + 1];
            float v22 = sIn[icl][ry + 2][rx + 2];
            const float* wrow = w + ((size_t)ocb * 128 + (ic0 + icl)) * 9;
            #pragma unroll
            for (int oct = 0; oct < OCT; ++oct) {
                const float* wp = wrow + (size_t)oct * 1152;  // 128*9
                float a = acc[oct];
                a = fmaf(v00, wp[0], a);
                a = fmaf(v01, wp[1], a);
                a = fmaf(v02, wp[2], a);
                a = fmaf(v10, wp[3], a);
                a = fmaf(v11, wp[4], a);
                a = fmaf(v12, wp[5], a);
                a = fmaf(v20, wp[6], a);
                a = fmaf(v21, wp[7], a);
                a = fmaf(v22, wp[8], a);
                acc[oct] = a;
            }
        }
        __syncthreads();
    }
    const int oy = blockIdx.y * 16 + ty, ox = blockIdx.x * 16 + tx;
    #pragma unroll
    for (int oct = 0; oct < OCT; ++oct) {
        float r = acc[oct] + bias[ocb + oct];
        if (RELU) r = lrelu(r);
        out[(((size_t)b * 128 + (ocb + oct)) * Hout + oy) * Wout + ox] = r;
    }
}

// ---------------- 2x nearest-neighbor upsample ----------------
__global__ __launch_bounds__(256) void up2d_kernel(
    const float* __restrict__ in, float* __restrict__ out, int Hout, int Wout, int total)
{
    int idx = blockIdx.x * 256 + threadIdx.x;
    if (idx >= total) return;
    int x = idx % Wout;
    int y = (idx / Wout) % Hout;
    int bc = idx / (Wout * Hout);
    out[idx] = in[((size_t)bc * (Hout / 2) + (y >> 1)) * (Wout / 2) + (x >> 1)];
}

// ---------------- per-pixel channel-norm + 1x1 sel conv ----------------
__global__ __launch_bounds__(256) void normsel_kernel(
    const float* __restrict__ h, const float* __restrict__ wsel,
    const float* __restrict__ bsel, float* __restrict__ s_lin, int total)
{
    int idx = blockIdx.x * 256 + threadIdx.x;
    if (idx >= total) return;
    int b = idx >> 14, pix = idx & 16383;
    const float* hb = h + (size_t)b * 128 * 16384 + pix;
    float ss = 0.f, dot = 0.f;
    #pragma unroll 8
    for (int c = 0; c < 128; ++c) {
        float v = hb[(size_t)c * 16384];
        ss = fmaf(v, v, ss);
        dot = fmaf(wsel[c], v, dot);
    }
    s_lin[idx] = dot / (sqrtf(ss) + 1e-8f) + bsel[0];
}

// ---------------- softmax over 16384, write feat_map ----------------
__global__ __launch_bounds__(256) void softmax_kernel(
    const float* __restrict__ s_lin, float* __restrict__ feat)
{
    int b = blockIdx.x;
    const float* src = s_lin + b * 16384;
    __shared__ float red[256];
    int tid = threadIdx.x;
    float m = -INFINITY;
    for (int i = tid; i < 16384; i += 256) m = fmaxf(m, src[i]);
    red[tid] = m;
    __syncthreads();
    for (int off = 128; off > 0; off >>= 1) {
        if (tid < off) red[tid] = fmaxf(red[tid], red[tid + off]);
        __syncthreads();
    }
    m = red[0];
    __syncthreads();
    float s = 0.f;
    for (int i = tid; i < 16384; i += 256) s += expf(src[i] - m);
    red[tid] = s;
    __syncthreads();
    for (int off = 128; off > 0; off >>= 1) {
        if (tid < off) red[tid] += red[tid + off];
        __syncthreads();
    }
    s = red[0];
    float inv = 1.f / s;
    for (int i = tid; i < 16384; i += 256) feat[b * 16384 + i] = expf(src[i] - m) * inv;
}

// ---------------- top-16 via iterated argmax (lower-index tie-break) ----------------
__global__ __launch_bounds__(256) void topk_kernel(
    const float* __restrict__ s_lin, float* __restrict__ scratch, int* __restrict__ idxOut)
{
    int b = blockIdx.x;
    const float* src = s_lin + b * 16384;
    float* scr = scratch + b * 16384;
    int tid = threadIdx.x;
    for (int i = tid; i < 16384; i += 256) scr[i] = src[i];
    __syncthreads();
    __shared__ float sv[256];
    __shared__ int si[256];
    for (int k = 0; k < 16; ++k) {
        float bv = -INFINITY;
        int bi_ = 0x7fffffff;
        for (int i = tid; i < 16384; i += 256) {
            float v = scr[i];
            if (v > bv || (v == bv && i < bi_)) { bv = v; bi_ = i; }
        }
        sv[tid] = bv; si[tid] = bi_;
        __syncthreads();
        for (int off = 128; off > 0; off >>= 1) {
            if (tid < off) {
                float v2 = sv[tid + off]; int i2 = si[tid + off];
                if (v2 > sv[tid] || (v2 == sv[tid] && i2 < si[tid])) { sv[tid] = v2; si[tid] = i2; }
            }
            __syncthreads();
        }
        if (tid == 0) {
            idxOut[b * 16 + k] = si[0];
            scr[si[0]] = -INFINITY;
        }
        __syncthreads();
    }
}

// ---------------- latents: 1x1 values-conv at 16 selected positions ----------------
__global__ __launch_bounds__(128) void latents_kernel(
    const float* __restrict__ h, const float* __restrict__ wval,
    const float* __restrict__ bval, const int* __restrict__ tki,
    float* __restrict__ outL, float* __restrict__ zbuf)
{
    int bk = blockIdx.x;          // b*16 + k
    int oc = threadIdx.x;         // 0..127
    int b = bk >> 4;
    int pix = tki[bk];
    const float* hb = h + (size_t)b * 128 * 16384 + pix;
    const float* wr = wval + oc * 128;
    float acc = bval[oc];
    #pragma unroll 8
    for (int ic = 0; ic < 128; ++ic) acc = fmaf(wr[ic], hb[(size_t)ic * 16384], acc);
    outL[bk * 128 + oc] = acc;
    zbuf[bk * 128 + oc] = acc;
}

// ---------------- up-projection z(32,128) @ wup(128,512) + bup ----------------
__global__ __launch_bounds__(256) void upproj_kernel(
    const float* __restrict__ zbuf, const float* __restrict__ wup,
    const float* __restrict__ bup, float* __restrict__ u0, int total)
{
    int idx = blockIdx.x * 256 + threadIdx.x;
    if (idx >= total) return;
    int a = idx >> 9, o = idx & 511;
    const float* z = zbuf + a * 128;
    float acc = bup[o];
    #pragma unroll 8
    for (int k = 0; k < 128; ++k) acc = fmaf(z[k], wup[k * 512 + o], acc);
    u0[idx] = acc;
}

// ---------------- conv1d on 2x-repeated input, k=3 pad=1, + lrelu ----------------
template<int LIN>
__global__ __launch_bounds__(256) void conv1dup_kernel(
    const float* __restrict__ in, const float* __restrict__ w,
    const float* __restrict__ bias, float* __restrict__ out, int total)
{
    constexpr int LOUT = 2 * LIN;
    constexpr int SH = (LIN == 4) ? 3 : (LIN == 8) ? 4 : 5;
    int idx = blockIdx.x * 256 + threadIdx.x;
    if (idx >= total) return;
    int t  = idx & (LOUT - 1);
    int oc = (idx >> SH) & 127;
    int a  = idx >> (SH + 7);
    float acc = bias[oc];
    const float* ib = in + (size_t)a * 128 * LIN;
    const float* wr = w + (size_t)oc * 384;
    int im_ = (t - 1) >> 1, i0 = t >> 1, ip = (t + 1) >> 1;
    bool bm = (t - 1) >= 0, bp = (t + 1) < LOUT;
    #pragma unroll 4
    for (int ic = 0; ic < 128; ++ic) {
        const float* ii = ib + ic * LIN;
        const float* ww = wr + ic * 3;
        if (bm) acc = fmaf(ww[0], ii[im_], acc);
        acc = fmaf(ww[1], ii[i0], acc);
        if (bp) acc = fmaf(ww[2], ii[ip], acc);
    }
    out[idx] = lrelu(acc);
}

// ---------------- pointwise conv1d heads: amp/mags (square) and fr (sigmoid) ----------------
template<int OC, int MODE>  // MODE 0 = square, 1 = sigmoid affine
__global__ __launch_bounds__(256) void pw_kernel(
    const float* __restrict__ in, const float* __restrict__ w,
    const float* __restrict__ bias, float* __restrict__ out, int total)
{
    int idx = blockIdx.x * 256 + threadIdx.x;
    if (idx >= total) return;
    int t  = idx & 31;
    int oc = (idx >> 5) % OC;
    int a  = idx / (32 * OC);
    const float* ib = in + (size_t)a * 128 * 32 + t;
    const float* wr = w + oc * 128;
    float acc = bias[oc];
    #pragma unroll 8
    for (int ic = 0; ic < 128; ++ic) acc = fmaf(wr[ic], ib[ic * 32], acc);
    if (MODE == 1) {
        float s = 1.f / (1.f + expf(-acc));
        acc = LOWEST_FREQ + s * (1.f - LOWEST_FREQ);
    } else {
        acc = acc * acc;
    }
    out[idx] = acc;
}

// ---------------- per-(a,c) phase-base prefix in double, reduced mod 1 rev ----------------
__global__ __launch_bounds__(256) void prefix_kernel(
    const float* __restrict__ fr, float* __restrict__ pb, int total)
{
    int i = blockIdx.x * 256 + threadIdx.x;   // a*128 + c
    if (i >= total) return;
    const float* f = fr + i * 32;
    float* p = pb + i * 32;
    double s = 0.0;
    for (int j = 0; j < 32; ++j) {
        double t = 128.0 * s;                 // revolutions accumulated by full blocks
        p[j] = (float)(t - floor(t));
        s += (double)f[j];
    }
}

// ---------------- harmonic synth + scatter-add ----------------
__global__ __launch_bounds__(256) void harm_kernel(
    const float* __restrict__ fr, const float* __restrict__ amp,
    const float* __restrict__ pb, const int* __restrict__ tki,
    float* __restrict__ outp, int total)
{
    int idx = blockIdx.x * 256 + threadIdx.x;
    if (idx >= total) return;
    int a = idx >> 13;
    int i = idx & 8191;
    int j = i >> 8;
    float il1 = (float)((i & 255) + 1);
    int base = a * 4096 + j;                  // (a*128 + c)*32 + j
    float acc = 0.f;
    #pragma unroll 4
    for (int c = 0; c < 128; ++c) {
        int o = base + c * 32;                // wave-uniform -> scalar loads
        float f = fr[o];
        float am = amp[o];
        float p = pb[o];
        float rev = fmaf(il1, 0.5f * f, p);   // phase in revolutions
        acc = fmaf(fast_sin_rev(rev), am, acc);
    }
    int b = a >> 4;
    atomicAdd(outp + (size_t)b * 32768 + tki[a] + i, acc);
}

// ---------------- direct rfft of noise (N=256) ----------------
__global__ __launch_bounds__(256) void spec_kernel(
    const float* __restrict__ noise, float* __restrict__ re,
    float* __restrict__ im, int total)
{
    int idx = blockIdx.x * 256 + threadIdx.x;
    if (idx >= total) return;
    int f  = idx % 129;
    int aw = idx / 129;
    const float* np_ = noise + (size_t)aw * 256;
    float sr = 0.f, si = 0.f;
    for (int n = 0; n < 256; ++n) {
        float rev = (float)(f * n) * (1.0f / 256.0f);
        float c = fast_cos_rev(rev);
        float s = fast_sin_rev(rev);
        float v = np_[n];
        sr = fmaf(v, c, sr);
        si = fmaf(v, -s, si);                 // exp(-i theta)
    }
    re[idx] = sr;
    im[idx] = si;
}

// ---------------- irfft(spec * mags) + scatter-add ----------------
__global__ __launch_bounds__(256) void nz_kernel(
    const float* __restrict__ re, const float* __restrict__ im,
    const float* __restrict__ mags, const int* __restrict__ tki,
    float* __restrict__ outp, int total)
{
    int idx = blockIdx.x * 256 + threadIdx.x;
    if (idx >= total) return;
    int t  = idx & 255;
    int w_ = (idx >> 8) & 31;
    int a  = idx >> 13;
    const float* R = re + ((size_t)a * 32 + w_) * 129;
    const float* I = im + ((size_t)a * 32 + w_) * 129;
    const float* M = mags + (size_t)a * 129 * 32 + w_;   // m[f] = M[f*32]
    float acc = R[0] * M[0];
    #pragma unroll 4
    for (int f = 1; f < 128; ++f) {
        float rev = (float)(f * t) * (1.0f / 256.0f);
        float c = fast_cos_rev(rev);
        float s = fast_sin_rev(rev);
        acc = fmaf(2.f * M[f * 32], fmaf(R[f], c, -I[f] * s), acc);
    }
    float sg = (t & 1) ? -1.f : 1.f;
    acc = fmaf(M[128 * 32] * sg, R[128], acc);
    acc *= (1.f / 256.f);
    int b = a >> 4;
    atomicAdd(outp + (size_t)b * 32768 + tki[a] + (w_ << 8) + t, acc);
}

extern "C" void kernel_launch(void* const* d_in, const int* in_sizes, int n_in,
                              void* d_out, int out_size, void* d_ws, size_t ws_size,
                              hipStream_t stream) {
    (void)n_in; (void)ws_size;
    const float* x    = (const float*)d_in[0];
    const float* pos  = (const float*)d_in[1];
    const float* wi   = (const float*)d_in[2];
    const float* bi   = (const float*)d_in[3];
    const float* wp   = (const float*)d_in[4];
    const float* bp   = (const float*)d_in[5];
    const float* ws1  = (const float*)d_in[6];
    const float* bs1  = (const float*)d_in[7];
    const float* ws2  = (const float*)d_in[8];
    const float* bs2  = (const float*)d_in[9];
    const float* ws3  = (const float*)d_in[10];
    const float* bs3  = (const float*)d_in[11];
    const float* ws4  = (const float*)d_in[12];
    const float* bs4  = (const float*)d_in[13];
    const float* wsb  = (const float*)d_in[14];
    const float* bsb  = (const float*)d_in[15];
    const float* wsel = (const float*)d_in[16];
    const float* bsel = (const float*)d_in[17];
    const float* wval = (const float*)d_in[18];
    const float* bval = (const float*)d_in[19];
    const float* wup  = (const float*)d_in[20];
    const float* bup  = (const float*)d_in[21];
    const float* wu1  = (const float*)d_in[22];
    const float* bu1  = (const float*)d_in[23];
    const float* wu2  = (const float*)d_in[24];
    const float* bu2  = (const float*)d_in[25];
    const float* wu3  = (const float*)d_in[26];
    const float* bu3  = (const float*)d_in[27];
    const float* wamp = (const float*)d_in[28];
    const float* bamp = (const float*)d_in[29];
    const float* wfr  = (const float*)d_in[30];
    const float* bfr  = (const float*)d_in[31];
    const float* wnz  = (const float*)d_in[32];
    const float* bnz  = (const float*)d_in[33];
    const float* noise= (const float*)d_in[34];

    const int B = in_sizes[0] / (128 * 128);   // = 2
    float* outp = (float*)d_out;
    float* outL = outp + (size_t)B * 32768;
    float* feat = outL + (size_t)B * 16 * 128;

    // workspace layout (floats). Two big ping-pong regions + smalls (smalls live
    // in the off1 region, only used after the conv chain is done with it).
    float* w0 = (float*)d_ws;
    const size_t BIG = (size_t)B * 128 * 128 * 128;    // 4,194,304 for B=2
    float* off0 = w0;
    float* off1 = w0 + BIG;
    float* s_lin = off1;                                // B*16384
    float* tscr  = s_lin + (size_t)B * 16384;           // B*16384
    int*   tki   = (int*)(tscr + (size_t)B * 16384);    // B*16
    float* zbuf  = (float*)(tki + 64);                  // B*16*128
    float* u0    = zbuf + (size_t)B * 2048;             // B*16*128*32 (also holds 32x512)
    float* u1    = u0 + (size_t)B * 65536;
    float* ampb  = u1 + (size_t)B * 65536;
    float* frb   = ampb + (size_t)B * 65536;
    float* pbb   = frb + (size_t)B * 65536;
    float* magsb = pbb + (size_t)B * 65536;             // B*16*129*32
    float* spR   = magsb + (size_t)B * 16 * 129 * 32;
    float* spI   = spR + (size_t)B * 16 * 32 * 129;

    hipMemsetAsync(d_out, 0, (size_t)out_size * sizeof(float), stream);

    // ---- encoder conv chain ----
    {
        int total = B * 128 * 16384;
        conv_in_kernel<<<(total + 255) / 256, 256, 0, stream>>>(x, wi, bi, pos, off0, total);
    }
    conv3x3_k<1, 8, 16, false><<<dim3(8, 8, B * 8), 256, 0, stream>>>(off0, wp, bp, off1, 128, 128);
    conv3x3_k<2, 4, 8,  true ><<<dim3(4, 4, B * 16), 256, 0, stream>>>(off1, ws1, bs1, off0, 128, 128);
    conv3x3_k<2, 4, 4,  true ><<<dim3(2, 2, B * 32), 256, 0, stream>>>(off0, ws2, bs2, off1, 64, 64);
    {
        int total = B * 128 * 64 * 64;
        up2d_kernel<<<(total + 255) / 256, 256, 0, stream>>>(off1, off0, 64, 64, total);
    }
    conv3x3_k<1, 8, 8,  true ><<<dim3(4, 4, B * 16), 256, 0, stream>>>(off0, ws3, bs3, off1, 64, 64);
    {
        int total = B * 128 * 128 * 128;
        up2d_kernel<<<(total + 255) / 256, 256, 0, stream>>>(off1, off0, 128, 128, total);
    }
    conv3x3_k<1, 8, 16, true ><<<dim3(8, 8, B * 8), 256, 0, stream>>>(off0, ws4, bs4, off1, 128, 128);
    conv3x3_k<1, 8, 16, false><<<dim3(8, 8, B * 8), 256, 0, stream>>>(off1, wsb, bsb, off0, 128, 128);
    float* h = off0;   // final feature map (B,128,128,128)

    // ---- selection ----
    {
        int total = B * 16384;
        normsel_kernel<<<(total + 255) / 256, 256, 0, stream>>>(h, wsel, bsel, s_lin, total);
    }
    softmax_kernel<<<B, 256, 0, stream>>>(s_lin, feat);
    topk_kernel<<<B, 256, 0, stream>>>(s_lin, tscr, tki);
    latents_kernel<<<B * 16, 128, 0, stream>>>(h, wval, bval, tki, outL, zbuf);

    // ---- decoder ----
    {
        int total = B * 16 * 512;
        upproj_kernel<<<(total + 255) / 256, 256, 0, stream>>>(zbuf, wup, bup, u0, total);
    }
    {
        int total = B * 16 * 128 * 8;
        conv1dup_kernel<4><<<(total + 255) / 256, 256, 0, stream>>>(u0, wu1, bu1, u1, total);
    }
    {
        int total = B * 16 * 128 * 16;
        conv1dup_kernel<8><<<(total + 255) / 256, 256, 0, stream>>>(u1, wu2, bu2, u0, total);
    }
    {
        int total = B * 16 * 128 * 32;
        conv1dup_kernel<16><<<(total + 255) / 256, 256, 0, stream>>>(u0, wu3, bu3, u1, total);
    }
    {
        int total = B * 16 * 128 * 32;
        pw_kernel<128, 0><<<(total + 255) / 256, 256, 0, stream>>>(u1, wamp, bamp, ampb, total);
        pw_kernel<128, 1><<<(total + 255) / 256, 256, 0, stream>>>(u1, wfr, bfr, frb, total);
    }
    {
        int total = B * 16 * 129 * 32;
        pw_kernel<129, 0><<<(total + 255) / 256, 256, 0, stream>>>(u1, wnz, bnz, magsb, total);
    }
    {
        int total = B * 16 * 128;
        prefix_kernel<<<(total + 255) / 256, 256, 0, stream>>>(frb, pbb, total);
    }
    {
        int total = B * 16 * 8192;
        harm_kernel<<<(total + 255) / 256, 256, 0, stream>>>(frb, ampb, pbb, tki, outp, total);
    }
    {
        int total = B * 16 * 32 * 129;
        spec_kernel<<<(total + 255) / 256, 256, 0, stream>>>(noise, spR, spI, total);
    }
    {
        int total = B * 16 * 32 * 256;
        nz_kernel<<<(total + 255) / 256, 256, 0, stream>>>(spR, spI, magsb, tki, outp, total);
    }
}

// Round 2
// 1394.845 us; speedup vs baseline: 1.4704x; 1.4704x over previous
//
#include <hip/hip_runtime.h>
#include <hip/hip_bf16.h>
#include <math.h>

#define LOWEST_FREQ (30.0f / 11025.0f)

__device__ __forceinline__ float fast_sin_rev(float rev) {
#if __has_builtin(__builtin_amdgcn_sinf)
    return __builtin_amdgcn_sinf(rev);   // v_sin_f32: sin(2*pi*rev)
#else
    return __sinf(rev * 6.28318530717958647692f);
#endif
}
__device__ __forceinline__ float fast_cos_rev(float rev) {
#if __has_builtin(__builtin_amdgcn_cosf)
    return __builtin_amdgcn_cosf(rev);
#else
    return __cosf(rev * 6.28318530717958647692f);
#endif
}
__device__ __forceinline__ float lrelu(float x) { return x >= 0.f ? x : 0.2f * x; }

// ---------------- conv_in: 1ch -> 112ch 3x3 + concat pos (16ch) ----------------
__global__ __launch_bounds__(256) void conv_in_kernel(
    const float* __restrict__ x, const float* __restrict__ wi,
    const float* __restrict__ bi, const float* __restrict__ pos,
    float* __restrict__ out, int total)
{
    int idx = blockIdx.x * 256 + threadIdx.x;
    if (idx >= total) return;
    int pix = idx & 16383;
    int c   = (idx >> 14) & 127;
    int b   = idx >> 21;
    int y = pix >> 7, xx = pix & 127;
    float v;
    if (c < 112) {
        float acc = bi[c];
        const float* xb = x + (size_t)b * 16384;
        const float* wc = wi + c * 9;
        #pragma unroll
        for (int ky = 0; ky < 3; ++ky) {
            int gy = y + ky - 1;
            if ((unsigned)gy < 128u) {
                #pragma unroll
                for (int kx = 0; kx < 3; ++kx) {
                    int gx = xx + kx - 1;
                    if ((unsigned)gx < 128u)
                        acc = fmaf(wc[ky * 3 + kx], xb[gy * 128 + gx], acc);
                }
            }
        }
        v = acc;
    } else {
        v = pos[(c - 112) * 16384 + pix];
    }
    out[idx] = v;
}

// ---------------- stride-1 3x3 conv, 128->128 ch, register-tiled ----------------
// 256 threads = 4 oc-groups (wave each) x 64 px-threads; each thread: 2x2 px x OCT oc.
// Block tile: 16x16 px, 4*OCT out-channels. Optional fused 2x nearest upsample on input.
template<int ICCH, int OCT, bool RELU, bool UP2>
__global__ __launch_bounds__(256) void conv3x3_s1(
    const float* __restrict__ in, const float* __restrict__ w,
    const float* __restrict__ bias, float* __restrict__ out,
    int Hin, int Win)   // logical (post-upsample) input dims == output dims
{
    __shared__ float sIn[ICCH][18][18];
    const int tid = threadIdx.x;
    const int pt  = tid & 63;
    const int ocg = __builtin_amdgcn_readfirstlane(tid >> 6);  // wave-uniform
    const int ry  = (pt >> 3) << 1;   // 0..14
    const int rx  = (pt & 7) << 1;    // 0..14
    constexpr int OC_TILE = OCT * 4;
    const int nOcb = 128 / OC_TILE;
    const int b    = blockIdx.z / nOcb;
    const int ocb  = (blockIdx.z % nOcb) * OC_TILE + ocg * OCT;  // wave-uniform
    const int iy0  = blockIdx.y * 16 - 1;
    const int ix0  = blockIdx.x * 16 - 1;
    const int Hp = UP2 ? (Hin >> 1) : Hin;
    const int Wp = UP2 ? (Win >> 1) : Win;
    const size_t HWp = (size_t)Hp * Wp;

    float acc[OCT][2][2];
    #pragma unroll
    for (int o = 0; o < OCT; ++o)
        #pragma unroll
        for (int i = 0; i < 2; ++i)
            #pragma unroll
            for (int j = 0; j < 2; ++j) acc[o][i][j] = 0.f;

    for (int ic0 = 0; ic0 < 128; ic0 += ICCH) {
        const float* inb = in + ((size_t)b * 128 + ic0) * HWp;
        constexpr int TOT = ICCH * 18 * 18;
        for (int s = tid; s < TOT; s += 256) {
            int icl = s / 324;
            int rem = s - icl * 324;
            int r = rem / 18;
            int c = rem - r * 18;
            int gy = iy0 + r, gx = ix0 + c;
            float v = 0.f;
            if ((unsigned)gy < (unsigned)Hin && (unsigned)gx < (unsigned)Win) {
                if (UP2) v = inb[icl * HWp + (size_t)(gy >> 1) * Wp + (gx >> 1)];
                else     v = inb[icl * HWp + (size_t)gy * Wp + gx];
            }
            sIn[icl][r][c] = v;
        }
        __syncthreads();
        #pragma unroll 2
        for (int icl = 0; icl < ICCH; ++icl) {
            float vin[4][4];
            #pragma unroll
            for (int i = 0; i < 4; ++i)
                #pragma unroll
                for (int j = 0; j < 4; ++j) vin[i][j] = sIn[icl][ry + i][rx + j];
            const float* wq = w + ((size_t)ocb * 128 + (ic0 + icl)) * 9;
            #pragma unroll
            for (int o = 0; o < OCT; ++o) {
                const float* wo = wq + (size_t)o * 1152;  // 128*9
                float w0 = wo[0], w1 = wo[1], w2 = wo[2];
                float w3 = wo[3], w4 = wo[4], w5 = wo[5];
                float w6 = wo[6], w7 = wo[7], w8 = wo[8];
                #pragma unroll
                for (int py = 0; py < 2; ++py)
                    #pragma unroll
                    for (int px = 0; px < 2; ++px) {
                        float a = acc[o][py][px];
                        a = fmaf(w0, vin[py + 0][px + 0], a);
                        a = fmaf(w1, vin[py + 0][px + 1], a);
                        a = fmaf(w2, vin[py + 0][px + 2], a);
                        a = fmaf(w3, vin[py + 1][px + 0], a);
                        a = fmaf(w4, vin[py + 1][px + 1], a);
                        a = fmaf(w5, vin[py + 1][px + 2], a);
                        a = fmaf(w6, vin[py + 2][px + 0], a);
                        a = fmaf(w7, vin[py + 2][px + 1], a);
                        a = fmaf(w8, vin[py + 2][px + 2], a);
                        acc[o][py][px] = a;
                    }
            }
        }
        __syncthreads();
    }
    const int oy0 = blockIdx.y * 16 + ry;
    const int ox0 = blockIdx.x * 16 + rx;
    #pragma unroll
    for (int o = 0; o < OCT; ++o) {
        float bv = bias[ocb + o];
        #pragma unroll
        for (int py = 0; py < 2; ++py)
            #pragma unroll
            for (int px = 0; px < 2; ++px) {
                float r = acc[o][py][px] + bv;
                if (RELU) r = lrelu(r);
                out[(((size_t)b * 128 + (ocb + o)) * Hin + (oy0 + py)) * Win + (ox0 + px)] = r;
            }
    }
}

// ---------------- stride-2 3x3 conv, 128->128 ch ----------------
// 256 threads = 4 oc-groups x 64 px-threads (8x8 out tile, 1 px each), OCT oc/thread.
template<int ICCH, int OCT, bool RELU>
__global__ __launch_bounds__(256) void conv3x3_s2(
    const float* __restrict__ in, const float* __restrict__ w,
    const float* __restrict__ bias, float* __restrict__ out,
    int Hin, int Win)
{
    __shared__ float sIn[ICCH][17][17];
    const int tid = threadIdx.x;
    const int pt  = tid & 63;
    const int ocg = __builtin_amdgcn_readfirstlane(tid >> 6);
    const int pyt = pt >> 3, pxt = pt & 7;
    constexpr int OC_TILE = OCT * 4;
    const int nOcb = 128 / OC_TILE;
    const int b    = blockIdx.z / nOcb;
    const int ocb  = (blockIdx.z % nOcb) * OC_TILE + ocg * OCT;
    const int Hout = Hin >> 1, Wout = Win >> 1;
    const int iy0  = blockIdx.y * 16 - 1;
    const int ix0  = blockIdx.x * 16 - 1;
    const size_t HW = (size_t)Hin * Win;

    float acc[OCT];
    #pragma unroll
    for (int o = 0; o < OCT; ++o) acc[o] = 0.f;

    for (int ic0 = 0; ic0 < 128; ic0 += ICCH) {
        const float* inb = in + ((size_t)b * 128 + ic0) * HW;
        constexpr int TOT = ICCH * 17 * 17;
        for (int s = tid; s < TOT; s += 256) {
            int icl = s / 289;
            int rem = s - icl * 289;
            int r = rem / 17;
            int c = rem - r * 17;
            int gy = iy0 + r, gx = ix0 + c;
            float v = 0.f;
            if ((unsigned)gy < (unsigned)Hin && (unsigned)gx < (unsigned)Win)
                v = inb[icl * HW + (size_t)gy * Win + gx];
            sIn[icl][r][c] = v;
        }
        __syncthreads();
        #pragma unroll 2
        for (int icl = 0; icl < ICCH; ++icl) {
            float vin[3][3];
            #pragma unroll
            for (int i = 0; i < 3; ++i)
                #pragma unroll
                for (int j = 0; j < 3; ++j) vin[i][j] = sIn[icl][2 * pyt + i][2 * pxt + j];
            const float* wq = w + ((size_t)ocb * 128 + (ic0 + icl)) * 9;
            #pragma unroll
            for (int o = 0; o < OCT; ++o) {
                const float* wo = wq + (size_t)o * 1152;
                float a = acc[o];
                a = fmaf(wo[0], vin[0][0], a);
                a = fmaf(wo[1], vin[0][1], a);
                a = fmaf(wo[2], vin[0][2], a);
                a = fmaf(wo[3], vin[1][0], a);
                a = fmaf(wo[4], vin[1][1], a);
                a = fmaf(wo[5], vin[1][2], a);
                a = fmaf(wo[6], vin[2][0], a);
                a = fmaf(wo[7], vin[2][1], a);
                a = fmaf(wo[8], vin[2][2], a);
                acc[o] = a;
            }
        }
        __syncthreads();
    }
    const int oy = blockIdx.y * 8 + pyt;
    const int ox = blockIdx.x * 8 + pxt;
    #pragma unroll
    for (int o = 0; o < OCT; ++o) {
        float r = acc[o] + bias[ocb + o];
        if (RELU) r = lrelu(r);
        out[(((size_t)b * 128 + (ocb + o)) * Hout + oy) * Wout + ox] = r;
    }
}

// ---------------- per-pixel channel-norm + 1x1 sel conv ----------------
__global__ __launch_bounds__(256) void normsel_kernel(
    const float* __restrict__ h, const float* __restrict__ wsel,
    const float* __restrict__ bsel, float* __restrict__ s_lin, int total)
{
    int idx = blockIdx.x * 256 + threadIdx.x;
    if (idx >= total) return;
    int b = idx >> 14, pix = idx & 16383;
    const float* hb = h + (size_t)b * 128 * 16384 + pix;
    float ss = 0.f, dot = 0.f;
    #pragma unroll 8
    for (int c = 0; c < 128; ++c) {
        float v = hb[(size_t)c * 16384];
        ss = fmaf(v, v, ss);
        dot = fmaf(wsel[c], v, dot);
    }
    s_lin[idx] = dot / (sqrtf(ss) + 1e-8f) + bsel[0];
}

// ---------------- softmax over 16384, write feat_map ----------------
__global__ __launch_bounds__(256) void softmax_kernel(
    const float* __restrict__ s_lin, float* __restrict__ feat)
{
    int b = blockIdx.x;
    const float* src = s_lin + b * 16384;
    __shared__ float red[256];
    int tid = threadIdx.x;
    float m = -INFINITY;
    for (int i = tid; i < 16384; i += 256) m = fmaxf(m, src[i]);
    red[tid] = m;
    __syncthreads();
    for (int off = 128; off > 0; off >>= 1) {
        if (tid < off) red[tid] = fmaxf(red[tid], red[tid + off]);
        __syncthreads();
    }
    m = red[0];
    __syncthreads();
    float s = 0.f;
    for (int i = tid; i < 16384; i += 256) s += expf(src[i] - m);
    red[tid] = s;
    __syncthreads();
    for (int off = 128; off > 0; off >>= 1) {
        if (tid < off) red[tid] += red[tid + off];
        __syncthreads();
    }
    s = red[0];
    float inv = 1.f / s;
    for (int i = tid; i < 16384; i += 256) feat[b * 16384 + i] = expf(src[i] - m) * inv;
}

// ---------------- top-16 via iterated argmax (lower-index tie-break) ----------------
__global__ __launch_bounds__(256) void topk_kernel(
    const float* __restrict__ s_lin, float* __restrict__ scratch, int* __restrict__ idxOut)
{
    int b = blockIdx.x;
    const float* src = s_lin + b * 16384;
    float* scr = scratch + b * 16384;
    int tid = threadIdx.x;
    for (int i = tid; i < 16384; i += 256) scr[i] = src[i];
    __syncthreads();
    __shared__ float sv[256];
    __shared__ int si[256];
    for (int k = 0; k < 16; ++k) {
        float bv = -INFINITY;
        int bi_ = 0x7fffffff;
        for (int i = tid; i < 16384; i += 256) {
            float v = scr[i];
            if (v > bv || (v == bv && i < bi_)) { bv = v; bi_ = i; }
        }
        sv[tid] = bv; si[tid] = bi_;
        __syncthreads();
        for (int off = 128; off > 0; off >>= 1) {
            if (tid < off) {
                float v2 = sv[tid + off]; int i2 = si[tid + off];
                if (v2 > sv[tid] || (v2 == sv[tid] && i2 < si[tid])) { sv[tid] = v2; si[tid] = i2; }
            }
            __syncthreads();
        }
        if (tid == 0) {
            idxOut[b * 16 + k] = si[0];
            scr[si[0]] = -INFINITY;
        }
        __syncthreads();
    }
}

// ---------------- latents: 1x1 values-conv at 16 selected positions ----------------
__global__ __launch_bounds__(128) void latents_kernel(
    const float* __restrict__ h, const float* __restrict__ wval,
    const float* __restrict__ bval, const int* __restrict__ tki,
    float* __restrict__ outL, float* __restrict__ zbuf)
{
    int bk = blockIdx.x;          // b*16 + k
    int oc = threadIdx.x;         // 0..127
    int b = bk >> 4;
    int pix = tki[bk];
    const float* hb = h + (size_t)b * 128 * 16384 + pix;
    const float* wr = wval + oc * 128;
    float acc = bval[oc];
    #pragma unroll 8
    for (int ic = 0; ic < 128; ++ic) acc = fmaf(wr[ic], hb[(size_t)ic * 16384], acc);
    outL[bk * 128 + oc] = acc;
    zbuf[bk * 128 + oc] = acc;
}

// ---------------- up-projection z(32,128) @ wup(128,512) + bup ----------------
__global__ __launch_bounds__(256) void upproj_kernel(
    const float* __restrict__ zbuf, const float* __restrict__ wup,
    const float* __restrict__ bup, float* __restrict__ u0, int total)
{
    int idx = blockIdx.x * 256 + threadIdx.x;
    if (idx >= total) return;
    int a = idx >> 9, o = idx & 511;
    const float* z = zbuf + a * 128;
    float acc = bup[o];
    #pragma unroll 8
    for (int k = 0; k < 128; ++k) acc = fmaf(z[k], wup[k * 512 + o], acc);
    u0[idx] = acc;
}

// ---------------- conv1d on 2x-repeated input, k=3 pad=1, + lrelu ----------------
template<int LIN>
__global__ __launch_bounds__(256) void conv1dup_kernel(
    const float* __restrict__ in, const float* __restrict__ w,
    const float* __restrict__ bias, float* __restrict__ out, int total)
{
    constexpr int LOUT = 2 * LIN;
    constexpr int SH = (LIN == 4) ? 3 : (LIN == 8) ? 4 : 5;
    int idx = blockIdx.x * 256 + threadIdx.x;
    if (idx >= total) return;
    int t  = idx & (LOUT - 1);
    int oc = (idx >> SH) & 127;
    int a  = idx >> (SH + 7);
    float acc = bias[oc];
    const float* ib = in + (size_t)a * 128 * LIN;
    const float* wr = w + (size_t)oc * 384;
    int im_ = (t - 1) >> 1, i0 = t >> 1, ip = (t + 1) >> 1;
    bool bm = (t - 1) >= 0, bp = (t + 1) < LOUT;
    #pragma unroll 4
    for (int ic = 0; ic < 128; ++ic) {
        const float* ii = ib + ic * LIN;
        const float* ww = wr + ic * 3;
        if (bm) acc = fmaf(ww[0], ii[im_], acc);
        acc = fmaf(ww[1], ii[i0], acc);
        if (bp) acc = fmaf(ww[2], ii[ip], acc);
    }
    out[idx] = lrelu(acc);
}

// ---------------- pointwise conv1d heads: amp/mags (square) and fr (sigmoid) ----------------
template<int OC, int MODE>  // MODE 0 = square, 1 = sigmoid affine
__global__ __launch_bounds__(256) void pw_kernel(
    const float* __restrict__ in, const float* __restrict__ w,
    const float* __restrict__ bias, float* __restrict__ out, int total)
{
    int idx = blockIdx.x * 256 + threadIdx.x;
    if (idx >= total) return;
    int t  = idx & 31;
    int oc = (idx >> 5) % OC;
    int a  = idx / (32 * OC);
    const float* ib = in + (size_t)a * 128 * 32 + t;
    const float* wr = w + oc * 128;
    float acc = bias[oc];
    #pragma unroll 8
    for (int ic = 0; ic < 128; ++ic) acc = fmaf(wr[ic], ib[ic * 32], acc);
    if (MODE == 1) {
        float s = 1.f / (1.f + expf(-acc));
        acc = LOWEST_FREQ + s * (1.f - LOWEST_FREQ);
    } else {
        acc = acc * acc;
    }
    out[idx] = acc;
}

// ---------------- per-(a,c) phase-base prefix in double, reduced mod 1 rev ----------------
__global__ __launch_bounds__(256) void prefix_kernel(
    const float* __restrict__ fr, float* __restrict__ pb, int total)
{
    int i = blockIdx.x * 256 + threadIdx.x;   // a*128 + c
    if (i >= total) return;
    const float* f = fr + i * 32;
    float* p = pb + i * 32;
    double s = 0.0;
    for (int j = 0; j < 32; ++j) {
        double t = 128.0 * s;                 // revolutions accumulated by full blocks
        p[j] = (float)(t - floor(t));
        s += (double)f[j];
    }
}

// ---------------- harmonic synth + scatter-add ----------------
__global__ __launch_bounds__(256) void harm_kernel(
    const float* __restrict__ fr, const float* __restrict__ amp,
    const float* __restrict__ pb, const int* __restrict__ tki,
    float* __restrict__ outp, int total)
{
    int idx = blockIdx.x * 256 + threadIdx.x;
    if (idx >= total) return;
    int a = idx >> 13;
    int i = idx & 8191;
    int j = i >> 8;
    float il1 = (float)((i & 255) + 1);
    int base = a * 4096 + j;                  // (a*128 + c)*32 + j
    float acc = 0.f;
    #pragma unroll 4
    for (int c = 0; c < 128; ++c) {
        int o = base + c * 32;                // wave-uniform -> scalar loads
        float f = fr[o];
        float am = amp[o];
        float p = pb[o];
        float rev = fmaf(il1, 0.5f * f, p);   // phase in revolutions
        acc = fmaf(fast_sin_rev(rev), am, acc);
    }
    int b = a >> 4;
    atomicAdd(outp + (size_t)b * 32768 + tki[a] + i, acc);
}

// ---------------- direct rfft of noise (N=256) ----------------
__global__ __launch_bounds__(256) void spec_kernel(
    const float* __restrict__ noise, float* __restrict__ re,
    float* __restrict__ im, int total)
{
    int idx = blockIdx.x * 256 + threadIdx.x;
    if (idx >= total) return;
    int f  = idx % 129;
    int aw = idx / 129;
    const float* np_ = noise + (size_t)aw * 256;
    float sr = 0.f, si = 0.f;
    for (int n = 0; n < 256; ++n) {
        float rev = (float)(f * n) * (1.0f / 256.0f);
        float c = fast_cos_rev(rev);
        float s = fast_sin_rev(rev);
        float v = np_[n];
        sr = fmaf(v, c, sr);
        si = fmaf(v, -s, si);                 // exp(-i theta)
    }
    re[idx] = sr;
    im[idx] = si;
}

// ---------------- irfft(spec * mags) + scatter-add ----------------
__global__ __launch_bounds__(256) void nz_kernel(
    const float* __restrict__ re, const float* __restrict__ im,
    const float* __restrict__ mags, const int* __restrict__ tki,
    float* __restrict__ outp, int total)
{
    int idx = blockIdx.x * 256 + threadIdx.x;
    if (idx >= total) return;
    int t  = idx & 255;
    int w_ = (idx >> 8) & 31;
    int a  = idx >> 13;
    const float* R = re + ((size_t)a * 32 + w_) * 129;
    const float* I = im + ((size_t)a * 32 + w_) * 129;
    const float* M = mags + (size_t)a * 129 * 32 + w_;   // m[f] = M[f*32]
    float acc = R[0] * M[0];
    #pragma unroll 4
    for (int f = 1; f < 128; ++f) {
        float rev = (float)(f * t) * (1.0f / 256.0f);
        float c = fast_cos_rev(rev);
        float s = fast_sin_rev(rev);
        acc = fmaf(2.f * M[f * 32], fmaf(R[f], c, -I[f] * s), acc);
    }
    float sg = (t & 1) ? -1.f : 1.f;
    acc = fmaf(M[128 * 32] * sg, R[128], acc);
    acc *= (1.f / 256.f);
    int b = a >> 4;
    atomicAdd(outp + (size_t)b * 32768 + tki[a] + (w_ << 8) + t, acc);
}

extern "C" void kernel_launch(void* const* d_in, const int* in_sizes, int n_in,
                              void* d_out, int out_size, void* d_ws, size_t ws_size,
                              hipStream_t stream) {
    (void)n_in; (void)ws_size;
    const float* x    = (const float*)d_in[0];
    const float* pos  = (const float*)d_in[1];
    const float* wi   = (const float*)d_in[2];
    const float* bi   = (const float*)d_in[3];
    const float* wp   = (const float*)d_in[4];
    const float* bp   = (const float*)d_in[5];
    const float* ws1  = (const float*)d_in[6];
    const float* bs1  = (const float*)d_in[7];
    const float* ws2  = (const float*)d_in[8];
    const float* bs2  = (const float*)d_in[9];
    const float* ws3  = (const float*)d_in[10];
    const float* bs3  = (const float*)d_in[11];
    const float* ws4  = (const float*)d_in[12];
    const float* bs4  = (const float*)d_in[13];
    const float* wsb  = (const float*)d_in[14];
    const float* bsb  = (const float*)d_in[15];
    const float* wsel = (const float*)d_in[16];
    const float* bsel = (const float*)d_in[17];
    const float* wval = (const float*)d_in[18];
    const float* bval = (const float*)d_in[19];
    const float* wup  = (const float*)d_in[20];
    const float* bup  = (const float*)d_in[21];
    const float* wu1  = (const float*)d_in[22];
    const float* bu1  = (const float*)d_in[23];
    const float* wu2  = (const float*)d_in[24];
    const float* bu2  = (const float*)d_in[25];
    const float* wu3  = (const float*)d_in[26];
    const float* bu3  = (const float*)d_in[27];
    const float* wamp = (const float*)d_in[28];
    const float* bamp = (const float*)d_in[29];
    const float* wfr  = (const float*)d_in[30];
    const float* bfr  = (const float*)d_in[31];
    const float* wnz  = (const float*)d_in[32];
    const float* bnz  = (const float*)d_in[33];
    const float* noise= (const float*)d_in[34];

    const int B = in_sizes[0] / (128 * 128);   // = 2
    float* outp = (float*)d_out;
    float* outL = outp + (size_t)B * 32768;
    float* feat = outL + (size_t)B * 16 * 128;

    float* w0 = (float*)d_ws;
    const size_t BIG = (size_t)B * 128 * 128 * 128;    // per ping-pong buffer
    float* off0 = w0;
    float* off1 = w0 + BIG;
    float* s_lin = off1;                                // reused after conv chain
    float* tscr  = s_lin + (size_t)B * 16384;
    int*   tki   = (int*)(tscr + (size_t)B * 16384);
    float* zbuf  = (float*)(tki + 64);
    float* u0    = zbuf + (size_t)B * 2048;
    float* u1    = u0 + (size_t)B * 65536;
    float* ampb  = u1 + (size_t)B * 65536;
    float* frb   = ampb + (size_t)B * 65536;
    float* pbb   = frb + (size_t)B * 65536;
    float* magsb = pbb + (size_t)B * 65536;
    float* spR   = magsb + (size_t)B * 16 * 129 * 32;
    float* spI   = spR + (size_t)B * 16 * 32 * 129;

    hipMemsetAsync(d_out, 0, (size_t)out_size * sizeof(float), stream);

    // ---- encoder conv chain (up2d fused into ws3/ws4 staging) ----
    {
        int total = B * 128 * 16384;
        conv_in_kernel<<<(total + 255) / 256, 256, 0, stream>>>(x, wi, bi, pos, off0, total);
    }
    conv3x3_s1<16, 8, false, false><<<dim3(8, 8, B * 4), 256, 0, stream>>>(off0, wp, bp, off1, 128, 128);
    conv3x3_s2<16, 8, true ><<<dim3(8, 8, B * 4), 256, 0, stream>>>(off1, ws1, bs1, off0, 128, 128);
    conv3x3_s2<16, 4, true ><<<dim3(4, 4, B * 8), 256, 0, stream>>>(off0, ws2, bs2, off1, 64, 64);
    conv3x3_s1<16, 4, true, true ><<<dim3(4, 4, B * 8), 256, 0, stream>>>(off1, ws3, bs3, off0, 64, 64);
    conv3x3_s1<16, 8, true, true ><<<dim3(8, 8, B * 4), 256, 0, stream>>>(off0, ws4, bs4, off1, 128, 128);
    conv3x3_s1<16, 8, false, false><<<dim3(8, 8, B * 4), 256, 0, stream>>>(off1, wsb, bsb, off0, 128, 128);
    float* h = off0;   // (B,128,128,128)

    // ---- selection ----
    {
        int total = B * 16384;
        normsel_kernel<<<(total + 255) / 256, 256, 0, stream>>>(h, wsel, bsel, s_lin, total);
    }
    softmax_kernel<<<B, 256, 0, stream>>>(s_lin, feat);
    topk_kernel<<<B, 256, 0, stream>>>(s_lin, tscr, tki);
    latents_kernel<<<B * 16, 128, 0, stream>>>(h, wval, bval, tki, outL, zbuf);

    // ---- decoder ----
    {
        int total = B * 16 * 512;
        upproj_kernel<<<(total + 255) / 256, 256, 0, stream>>>(zbuf, wup, bup, u0, total);
    }
    {
        int total = B * 16 * 128 * 8;
        conv1dup_kernel<4><<<(total + 255) / 256, 256, 0, stream>>>(u0, wu1, bu1, u1, total);
    }
    {
        int total = B * 16 * 128 * 16;
        conv1dup_kernel<8><<<(total + 255) / 256, 256, 0, stream>>>(u1, wu2, bu2, u0, total);
    }
    {
        int total = B * 16 * 128 * 32;
        conv1dup_kernel<16><<<(total + 255) / 256, 256, 0, stream>>>(u0, wu3, bu3, u1, total);
    }
    {
        int total = B * 16 * 128 * 32;
        pw_kernel<128, 0><<<(total + 255) / 256, 256, 0, stream>>>(u1, wamp, bamp, ampb, total);
        pw_kernel<128, 1><<<(total + 255) / 256, 256, 0, stream>>>(u1, wfr, bfr, frb, total);
    }
    {
        int total = B * 16 * 129 * 32;
        pw_kernel<129, 0><<<(total + 255) / 256, 256, 0, stream>>>(u1, wnz, bnz, magsb, total);
    }
    {
        int total = B * 16 * 128;
        prefix_kernel<<<(total + 255) / 256, 256, 0, stream>>>(frb, pbb, total);
    }
    {
        int total = B * 16 * 8192;
        harm_kernel<<<(total + 255) / 256, 256, 0, stream>>>(frb, ampb, pbb, tki, outp, total);
    }
    {
        int total = B * 16 * 32 * 129;
        spec_kernel<<<(total + 255) / 256, 256, 0, stream>>>(noise, spR, spI, total);
    }
    {
        int total = B * 16 * 32 * 256;
        nz_kernel<<<(total + 255) / 256, 256, 0, stream>>>(spR, spI, magsb, tki, outp, total);
    }
}